// Round 1
// baseline (2121.049 us; speedup 1.0000x reference)
//
#include <hip/hip_runtime.h>
#include <math.h>

#define HIDDEN 64
#define N_LAYERS 4
#define N_CLASSES 10
#define N_GRAPHS 512

// ---------------- degree ----------------
__global__ __launch_bounds__(256) void k_deg_init(float* __restrict__ deg, int n) {
    int i = blockIdx.x * 256 + threadIdx.x;
    if (i < n) deg[i] = 1.0f;  // self-loop
}

__global__ __launch_bounds__(256) void k_deg_count(const int* __restrict__ dst,
                                                   float* __restrict__ deg, int E) {
    int i = blockIdx.x * 256 + threadIdx.x;
    if (i < E) atomicAdd(&deg[dst[i]], 1.0f);
}

__global__ __launch_bounds__(256) void k_deg_finish(const float* __restrict__ deg,
                                                    float* __restrict__ dis,
                                                    float* __restrict__ dinv, int n) {
    int i = blockIdx.x * 256 + threadIdx.x;
    if (i < n) {
        float d = deg[i];
        dis[i]  = rsqrtf(d);
        dinv[i] = 1.0f / d;
    }
}

// ---------------- GEMM: [N,64] @ [64,64] (+bias / +agg-init) ----------------
// mode 0: out_hl[r][c] = sum + bias[c]                       (encoder)
// mode 1: out_hl[r][c] = sum;  out_agg[r][c] = sum*dinv[r] + bias[c]   (conv)
// NOTE: out_agg may alias `in` — each block reads only the 16 rows it writes,
// and all reads complete (into LDS) before any writes.
__global__ __launch_bounds__(256) void k_gemm64(const float* __restrict__ in,
                                                const float* __restrict__ W,
                                                const float* __restrict__ bias,
                                                const float* __restrict__ dinv,
                                                float* __restrict__ out_hl,
                                                float* __restrict__ out_agg,
                                                int N, int mode) {
    __shared__ float Ws[64 * 64];
    __shared__ float Xs[16 * 64];
    int tid = threadIdx.x;
    #pragma unroll
    for (int i = 0; i < 16; ++i) Ws[tid + i * 256] = W[tid + i * 256];
    int row0 = blockIdx.x * 16;
    #pragma unroll
    for (int i = 0; i < 4; ++i) {
        int idx = tid + i * 256;            // 0..1023
        int r   = row0 + (idx >> 6);
        Xs[idx] = (r < N) ? in[r * 64 + (idx & 63)] : 0.0f;
    }
    __syncthreads();

    int c    = tid & 63;
    int rsub = (tid >> 6) * 4;              // 0,4,8,12
    float a0 = 0.f, a1 = 0.f, a2 = 0.f, a3 = 0.f;
    #pragma unroll
    for (int k = 0; k < 64; ++k) {
        float w = Ws[k * 64 + c];
        a0 += Xs[(rsub + 0) * 64 + k] * w;
        a1 += Xs[(rsub + 1) * 64 + k] * w;
        a2 += Xs[(rsub + 2) * 64 + k] * w;
        a3 += Xs[(rsub + 3) * 64 + k] * w;
    }
    float b = bias[c];
    float acc[4] = {a0, a1, a2, a3};
    #pragma unroll
    for (int i = 0; i < 4; ++i) {
        int r = row0 + rsub + i;
        if (r < N) {
            float v = acc[i];
            if (mode == 0) {
                out_hl[r * 64 + c] = v + b;
            } else {
                out_hl[r * 64 + c]  = v;
                out_agg[r * 64 + c] = v * dinv[r] + b;
            }
        }
    }
}

// ---------------- edge scatter: agg[dst] += hl[src] * dis[src]*dis[dst] ----------------
__global__ __launch_bounds__(256) void k_edge(const int* __restrict__ src,
                                              const int* __restrict__ dst,
                                              const float* __restrict__ dis,
                                              const float* __restrict__ hl,
                                              float* __restrict__ agg, int E) {
    int e = blockIdx.x * 4 + (threadIdx.x >> 6);
    if (e >= E) return;
    int j = threadIdx.x & 63;
    int s = src[e], d = dst[e];
    float norm = dis[s] * dis[d];
    atomicAdd(&agg[d * 64 + j], hl[s * 64 + j] * norm);
}

// ---------------- SiLU in-place ----------------
__global__ __launch_bounds__(256) void k_silu(float* __restrict__ a, int n) {
    int i = blockIdx.x * 256 + threadIdx.x;
    if (i < n) {
        float x = a[i];
        a[i] = x / (1.0f + expf(-x));
    }
}

// ---------------- pooling: pooled[batch[i]] += h[i] ----------------
__global__ __launch_bounds__(256) void k_pool(const float* __restrict__ h,
                                              const int* __restrict__ batch,
                                              float* __restrict__ pooled, int n) {
    int i = blockIdx.x * 4 + (threadIdx.x >> 6);
    if (i >= n) return;
    int j = threadIdx.x & 63;
    atomicAdd(&pooled[batch[i] * 64 + j], h[i * 64 + j]);
}

// ---------------- readout: relu(pooled @ W_out + b_out) ----------------
__global__ __launch_bounds__(256) void k_readout(const float* __restrict__ pooled,
                                                 const float* __restrict__ Wout,
                                                 const float* __restrict__ bout,
                                                 float* __restrict__ out) {
    int idx = blockIdx.x * 256 + threadIdx.x;
    if (idx >= N_GRAPHS * N_CLASSES) return;
    int g = idx / N_CLASSES, c = idx % N_CLASSES;
    float s = bout[c];
    #pragma unroll
    for (int j = 0; j < 64; ++j) s += pooled[g * 64 + j] * Wout[j * N_CLASSES + c];
    out[idx] = fmaxf(s, 0.0f);
}

extern "C" void kernel_launch(void* const* d_in, const int* in_sizes, int n_in,
                              void* d_out, int out_size, void* d_ws, size_t ws_size,
                              hipStream_t stream) {
    const float* x      = (const float*)d_in[0];
    const int*   ei     = (const int*)d_in[1];
    const int*   batch  = (const int*)d_in[2];
    const float* W_enc  = (const float*)d_in[3];
    const float* b_enc  = (const float*)d_in[4];
    const float* W_conv = (const float*)d_in[5];
    const float* b_conv = (const float*)d_in[6];
    const float* W_out  = (const float*)d_in[7];
    const float* b_out  = (const float*)d_in[8];
    float* out = (float*)d_out;

    const int N = in_sizes[2];
    const int E = in_sizes[1] / 2;
    const int* src = ei;
    const int* dst = ei + E;

    char* ws = (char*)d_ws;
    size_t off = 0;
    auto alloc = [&](size_t bytes) -> char* {
        char* p = ws + off;
        off += (bytes + 255) & ~(size_t)255;
        return p;
    };
    float* deg    = (float*)alloc((size_t)N * sizeof(float));
    float* dis    = (float*)alloc((size_t)N * sizeof(float));
    float* dinv   = (float*)alloc((size_t)N * sizeof(float));
    float* A      = (float*)alloc((size_t)N * HIDDEN * sizeof(float));  // h / agg
    float* B      = (float*)alloc((size_t)N * HIDDEN * sizeof(float));  // hl
    float* pooled = (float*)alloc((size_t)N_GRAPHS * HIDDEN * sizeof(float));
    (void)ws_size;

    int nb_n = (N + 255) / 256;
    int nb_e = (E + 255) / 256;
    k_deg_init  <<<nb_n, 256, 0, stream>>>(deg, N);
    k_deg_count <<<nb_e, 256, 0, stream>>>(dst, deg, E);
    k_deg_finish<<<nb_n, 256, 0, stream>>>(deg, dis, dinv, N);

    int gb = (N + 15) / 16;
    // encoder: A = x @ W_enc + b_enc
    k_gemm64<<<gb, 256, 0, stream>>>(x, W_enc, b_enc, nullptr, A, nullptr, N, 0);

    for (int l = 0; l < N_LAYERS; ++l) {
        // B = A @ W_conv[l];  A = B*dinv + b_conv[l]   (agg init, aliased safely)
        k_gemm64<<<gb, 256, 0, stream>>>(A, W_conv + (size_t)l * HIDDEN * HIDDEN,
                                         b_conv + (size_t)l * HIDDEN, dinv, B, A, N, 1);
        // A[dst] += B[src] * dis[src]*dis[dst]
        k_edge<<<(E + 3) / 4, 256, 0, stream>>>(src, dst, dis, B, A, E);
        // A = silu(A)
        k_silu<<<((size_t)N * HIDDEN + 255) / 256, 256, 0, stream>>>(A, N * HIDDEN);
    }

    hipMemsetAsync(pooled, 0, (size_t)N_GRAPHS * HIDDEN * sizeof(float), stream);
    k_pool<<<(N + 3) / 4, 256, 0, stream>>>(A, batch, pooled, N);
    k_readout<<<(N_GRAPHS * N_CLASSES + 255) / 256, 256, 0, stream>>>(pooled, W_out, b_out, out);
}

// Round 2
// 1044.549 us; speedup vs baseline: 2.0306x; 2.0306x over previous
//
#include <hip/hip_runtime.h>
#include <math.h>

#define HIDDEN 64
#define N_LAYERS 4
#define N_CLASSES 10
#define N_GRAPHS 512

// ---------------- degree count (int) ----------------
__global__ __launch_bounds__(256) void k_count(const int* __restrict__ dst,
                                               int* __restrict__ cnt, int E) {
    int i = blockIdx.x * 256 + threadIdx.x;
    if (i < E) atomicAdd(&cnt[dst[i]], 1);
}

__global__ __launch_bounds__(256) void k_deg_finish(const int* __restrict__ cnt,
                                                    float* __restrict__ dis,
                                                    float* __restrict__ dinv, int n) {
    int i = blockIdx.x * 256 + threadIdx.x;
    if (i < n) {
        float d = (float)cnt[i] + 1.0f;   // + self-loop
        dis[i]  = rsqrtf(d);
        dinv[i] = 1.0f / d;
    }
}

// ---------------- exclusive scan over cnt -> rowptr (1024 elems/block) ----------------
__global__ __launch_bounds__(256) void k_scan1(const int* __restrict__ cnt,
                                               int* __restrict__ partial, int n) {
    __shared__ int sd[256];
    int t = threadIdx.x;
    int base = blockIdx.x * 1024 + t * 4;
    int sum = 0;
    #pragma unroll
    for (int i = 0; i < 4; ++i) { int idx = base + i; if (idx < n) sum += cnt[idx]; }
    sd[t] = sum; __syncthreads();
    for (int o = 128; o > 0; o >>= 1) { if (t < o) sd[t] += sd[t + o]; __syncthreads(); }
    if (t == 0) partial[blockIdx.x] = sd[0];
}

__global__ __launch_bounds__(256) void k_scan2(int* __restrict__ partial, int nb) {
    __shared__ int s[256];
    int t = threadIdx.x;
    int v = (t < nb) ? partial[t] : 0;
    s[t] = v; __syncthreads();
    for (int o = 1; o < 256; o <<= 1) {
        int x = (t >= o) ? s[t - o] : 0;
        __syncthreads();
        s[t] += x;
        __syncthreads();
    }
    if (t < nb) partial[t] = s[t] - v;   // exclusive
}

__global__ __launch_bounds__(256) void k_scan3(const int* __restrict__ cnt,
                                               const int* __restrict__ partial,
                                               int* __restrict__ rowptr, int n, int E) {
    __shared__ int s[256];
    int t = threadIdx.x;
    int base = blockIdx.x * 1024 + t * 4;
    int v[4]; int tsum = 0;
    #pragma unroll
    for (int i = 0; i < 4; ++i) { int idx = base + i; v[i] = (idx < n) ? cnt[idx] : 0; tsum += v[i]; }
    s[t] = tsum; __syncthreads();
    int inc = tsum;
    for (int o = 1; o < 256; o <<= 1) {
        int x = (t >= o) ? s[t - o] : 0;
        __syncthreads();
        s[t] += x;
        __syncthreads();
    }
    inc = s[t];
    int run = partial[blockIdx.x] + inc - tsum;   // exclusive offset
    #pragma unroll
    for (int i = 0; i < 4; ++i) { int idx = base + i; if (idx < n) rowptr[idx] = run; run += v[i]; }
    if (blockIdx.x == 0 && t == 0) rowptr[n] = E;
}

// ---------------- CSR fill ----------------
__global__ __launch_bounds__(256) void k_fill(const int* __restrict__ src,
                                              const int* __restrict__ dst,
                                              const int* __restrict__ rowptr,
                                              int* __restrict__ tmp,
                                              int* __restrict__ csr_src, int E) {
    int e = blockIdx.x * 256 + threadIdx.x;
    if (e < E) {
        int d = dst[e];
        int p = rowptr[d] + atomicAdd(&tmp[d], 1);
        csr_src[p] = src[e];
    }
}

// ---------------- GEMM: [N,64] @ [64,64] ----------------
// mode 0: out_hl = sum + bias                         (encoder)
// mode 1: out_hl = sum * dis[r]  (pre-scaled message)
//         out_pre = sum * dinv[r] + bias              (self-loop + bias init)
__global__ __launch_bounds__(256) void k_gemm64(const float* __restrict__ in,
                                                const float* __restrict__ W,
                                                const float* __restrict__ bias,
                                                const float* __restrict__ dis,
                                                const float* __restrict__ dinv,
                                                float* __restrict__ out_hl,
                                                float* __restrict__ out_pre,
                                                int N, int mode) {
    __shared__ float Ws[64 * 64];
    __shared__ float Xs[16 * 64];
    int tid = threadIdx.x;
    #pragma unroll
    for (int i = 0; i < 16; ++i) Ws[tid + i * 256] = W[tid + i * 256];
    int row0 = blockIdx.x * 16;
    #pragma unroll
    for (int i = 0; i < 4; ++i) {
        int idx = tid + i * 256;
        int r   = row0 + (idx >> 6);
        Xs[idx] = (r < N) ? in[r * 64 + (idx & 63)] : 0.0f;
    }
    __syncthreads();

    int c    = tid & 63;
    int rsub = (tid >> 6) * 4;
    float a0 = 0.f, a1 = 0.f, a2 = 0.f, a3 = 0.f;
    #pragma unroll
    for (int k = 0; k < 64; ++k) {
        float w = Ws[k * 64 + c];
        a0 += Xs[(rsub + 0) * 64 + k] * w;
        a1 += Xs[(rsub + 1) * 64 + k] * w;
        a2 += Xs[(rsub + 2) * 64 + k] * w;
        a3 += Xs[(rsub + 3) * 64 + k] * w;
    }
    float b = bias[c];
    float acc[4] = {a0, a1, a2, a3};
    #pragma unroll
    for (int i = 0; i < 4; ++i) {
        int r = row0 + rsub + i;
        if (r < N) {
            float v = acc[i];
            if (mode == 0) {
                out_hl[r * 64 + c] = v + b;
            } else {
                out_hl[r * 64 + c]  = v * dis[r];
                out_pre[r * 64 + c] = v * dinv[r] + b;
            }
        }
    }
}

// ---------------- gather + self-loop + SiLU ----------------
// out[d] = silu( dis[d] * sum_{e in CSR[d]} hls[src_e]  +  pre[d] )
// One wave per node: 4 edge-groups x 16 feature-quads (float4/lane).
__global__ __launch_bounds__(256) void k_gather(const int* __restrict__ csr_src,
                                                const int* __restrict__ rowptr,
                                                const float* __restrict__ dis,
                                                const float* __restrict__ hls,
                                                const float* __restrict__ pre,
                                                float* __restrict__ out, int N) {
    int node = blockIdx.x * 4 + (threadIdx.x >> 6);
    if (node >= N) return;
    int lane = threadIdx.x & 63;
    int grp  = lane >> 4;      // 0..3
    int f4   = lane & 15;      // feature quad
    int beg  = rowptr[node];
    int num  = rowptr[node + 1] - beg;

    float ax = 0.f, ay = 0.f, az = 0.f, aw = 0.f;
    for (int i = grp; i < num; i += 4) {
        int s = csr_src[beg + i];
        float4 v = ((const float4*)(hls + (size_t)s * 64))[f4];
        ax += v.x; ay += v.y; az += v.z; aw += v.w;
    }
    // reduce across the 4 edge-groups (lanes differing in bits 4,5)
    ax += __shfl_xor(ax, 16); ay += __shfl_xor(ay, 16);
    az += __shfl_xor(az, 16); aw += __shfl_xor(aw, 16);
    ax += __shfl_xor(ax, 32); ay += __shfl_xor(ay, 32);
    az += __shfl_xor(az, 32); aw += __shfl_xor(aw, 32);

    if (grp == 0) {
        float dd = dis[node];
        float4 p = ((const float4*)(pre + (size_t)node * 64))[f4];
        float rx = dd * ax + p.x;
        float ry = dd * ay + p.y;
        float rz = dd * az + p.z;
        float rw = dd * aw + p.w;
        float4 r;
        r.x = rx / (1.0f + expf(-rx));
        r.y = ry / (1.0f + expf(-ry));
        r.z = rz / (1.0f + expf(-rz));
        r.w = rw / (1.0f + expf(-rw));
        ((float4*)(out + (size_t)node * 64))[f4] = r;
    }
}

// ---------------- pooling ----------------
__global__ __launch_bounds__(256) void k_pool(const float* __restrict__ h,
                                              const int* __restrict__ batch,
                                              float* __restrict__ pooled, int n) {
    int i = blockIdx.x * 4 + (threadIdx.x >> 6);
    if (i >= n) return;
    int j = threadIdx.x & 63;
    atomicAdd(&pooled[batch[i] * 64 + j], h[i * 64 + j]);
}

// ---------------- readout ----------------
__global__ __launch_bounds__(256) void k_readout(const float* __restrict__ pooled,
                                                 const float* __restrict__ Wout,
                                                 const float* __restrict__ bout,
                                                 float* __restrict__ out) {
    int idx = blockIdx.x * 256 + threadIdx.x;
    if (idx >= N_GRAPHS * N_CLASSES) return;
    int g = idx / N_CLASSES, c = idx % N_CLASSES;
    float s = bout[c];
    #pragma unroll
    for (int j = 0; j < 64; ++j) s += pooled[g * 64 + j] * Wout[j * N_CLASSES + c];
    out[idx] = fmaxf(s, 0.0f);
}

extern "C" void kernel_launch(void* const* d_in, const int* in_sizes, int n_in,
                              void* d_out, int out_size, void* d_ws, size_t ws_size,
                              hipStream_t stream) {
    const float* x      = (const float*)d_in[0];
    const int*   ei     = (const int*)d_in[1];
    const int*   batch  = (const int*)d_in[2];
    const float* W_enc  = (const float*)d_in[3];
    const float* b_enc  = (const float*)d_in[4];
    const float* W_conv = (const float*)d_in[5];
    const float* b_conv = (const float*)d_in[6];
    const float* W_out  = (const float*)d_in[7];
    const float* b_out  = (const float*)d_in[8];
    float* out = (float*)d_out;

    const int N = in_sizes[2];
    const int E = in_sizes[1] / 2;
    const int* src = ei;
    const int* dst = ei + E;

    char* ws = (char*)d_ws;
    size_t off = 0;
    auto alloc = [&](size_t bytes) -> char* {
        char* p = ws + off;
        off += (bytes + 255) & ~(size_t)255;
        return p;
    };
    int*   cnt     = (int*)alloc((size_t)N * sizeof(int));
    int*   tmp     = (int*)alloc((size_t)N * sizeof(int));
    int*   rowptr  = (int*)alloc((size_t)(N + 1) * sizeof(int));
    int*   partial = (int*)alloc(1024 * sizeof(int));
    int*   csr_src = (int*)alloc((size_t)E * sizeof(int));
    float* dis     = (float*)alloc((size_t)N * sizeof(float));
    float* dinv    = (float*)alloc((size_t)N * sizeof(float));
    float* A       = (float*)alloc((size_t)N * HIDDEN * sizeof(float));  // h
    float* B       = (float*)alloc((size_t)N * HIDDEN * sizeof(float));  // hl * dis
    float* P       = (float*)alloc((size_t)N * HIDDEN * sizeof(float));  // hl*dinv + b
    float* pooled  = (float*)alloc((size_t)N_GRAPHS * HIDDEN * sizeof(float));
    (void)ws_size;

    int nb_n = (N + 255) / 256;
    int nb_e = (E + 255) / 256;
    int nb_s = (N + 1023) / 1024;   // scan blocks (<=256 required; 98 here)

    hipMemsetAsync(cnt, 0, (size_t)N * sizeof(int), stream);
    hipMemsetAsync(tmp, 0, (size_t)N * sizeof(int), stream);
    hipMemsetAsync(pooled, 0, (size_t)N_GRAPHS * HIDDEN * sizeof(float), stream);

    k_count     <<<nb_e, 256, 0, stream>>>(dst, cnt, E);
    k_deg_finish<<<nb_n, 256, 0, stream>>>(cnt, dis, dinv, N);
    k_scan1     <<<nb_s, 256, 0, stream>>>(cnt, partial, N);
    k_scan2     <<<1,    256, 0, stream>>>(partial, nb_s);
    k_scan3     <<<nb_s, 256, 0, stream>>>(cnt, partial, rowptr, N, E);
    k_fill      <<<nb_e, 256, 0, stream>>>(src, dst, rowptr, tmp, csr_src, E);

    int gb = (N + 15) / 16;
    // encoder: A = x @ W_enc + b_enc
    k_gemm64<<<gb, 256, 0, stream>>>(x, W_enc, b_enc, nullptr, nullptr, A, nullptr, N, 0);

    for (int l = 0; l < N_LAYERS; ++l) {
        // B = (A @ Wl) * dis ;  P = (A @ Wl) * dinv + bl
        k_gemm64<<<gb, 256, 0, stream>>>(A, W_conv + (size_t)l * HIDDEN * HIDDEN,
                                         b_conv + (size_t)l * HIDDEN, dis, dinv, B, P, N, 1);
        // A = silu( dis * gather(B) + P )
        k_gather<<<(N + 3) / 4, 256, 0, stream>>>(csr_src, rowptr, dis, B, P, A, N);
    }

    k_pool<<<(N + 3) / 4, 256, 0, stream>>>(A, batch, pooled, N);
    k_readout<<<(N_GRAPHS * N_CLASSES + 255) / 256, 256, 0, stream>>>(pooled, W_out, b_out, out);
}